// Round 11
// baseline (271.741 us; speedup 1.0000x reference)
//
#include <hip/hip_runtime.h>
#include <stdint.h>
#include <stddef.h>

using short8 = __attribute__((ext_vector_type(8))) short;
using short4v = __attribute__((ext_vector_type(4))) short;
using f32x4  = __attribute__((ext_vector_type(4))) float;
using f32x16 = __attribute__((ext_vector_type(16))) float;
using bf16x8 = __attribute__((ext_vector_type(8))) __bf16;

#define DEVI __device__ __forceinline__

// round-to-nearest-even fp32 -> bf16 (bit pattern as short)
DEVI short bf16r(float f) {
  union { float f; uint32_t u; } x; x.f = f;
  uint32_t r = x.u + 0x7FFFu + ((x.u >> 16) & 1u);
  return (short)(r >> 16);
}

DEVI f32x4 mfma16(short8 a, short8 b, f32x4 c) {
  return __builtin_amdgcn_mfma_f32_16x16x32_bf16(
      __builtin_bit_cast(bf16x8, a), __builtin_bit_cast(bf16x8, b), c, 0, 0, 0);
}

DEVI f32x16 mfma32(short8 a, short8 b, f32x16 c) {
  return __builtin_amdgcn_mfma_f32_32x32x16_bf16(
      __builtin_bit_cast(bf16x8, a), __builtin_bit_cast(bf16x8, b), c, 0, 0, 0);
}

DEVI void gload_lds16(const void* g, void* l) {
  __builtin_amdgcn_global_load_lds(
      (const void __attribute__((address_space(1)))*)g,
      (void __attribute__((address_space(3)))*)l,
      16, 0, 0);
}

// v_exp_f32 computes 2^x
DEVI float fexp2(float x) {
  float r;
  asm("v_exp_f32 %0, %1" : "=v"(r) : "v"(x));
  return r;
}

// packed fp32->bf16: dst[15:0]=bf16(a), dst[31:16]=bf16(b)
DEVI unsigned cvtpk(float a, float b) {
  unsigned r;
  asm("v_cvt_pk_bf16_f32 %0, %1, %2" : "=v"(r) : "v"(a), "v"(b));
  return r;
}

// pairwise-tree reductions (short dependency chains; fp reorder only)
DEVI float max16(const f32x16& v) {
  float a = fmaxf(fmaxf(v[0], v[1]), fmaxf(v[2], v[3]));
  float b = fmaxf(fmaxf(v[4], v[5]), fmaxf(v[6], v[7]));
  float c = fmaxf(fmaxf(v[8], v[9]), fmaxf(v[10], v[11]));
  float d = fmaxf(fmaxf(v[12], v[13]), fmaxf(v[14], v[15]));
  return fmaxf(fmaxf(a, b), fmaxf(c, d));
}
DEVI float sum16(const f32x16& v) {
  float a = (v[0] + v[1]) + (v[2] + v[3]);
  float b = (v[4] + v[5]) + (v[6] + v[7]);
  float c = (v[8] + v[9]) + (v[10] + v[11]);
  float d = (v[12] + v[13]) + (v[14] + v[15]);
  return (a + b) + (c + d);
}

// ---------------- fp32 -> bf16 conversions ----------------
// 4 weight tensors in one dispatch: z in 0..3; z<2 big (n_big), z>=2 small (n_small)
__global__ void k_cvtw(const float* __restrict__ s0, short* __restrict__ d0,
                       const float* __restrict__ s1, short* __restrict__ d1,
                       const float* __restrict__ s2, short* __restrict__ d2,
                       const float* __restrict__ s3, short* __restrict__ d3,
                       int n_big, int n_small) {
  const int z = blockIdx.z;
  const float* s = (z == 0) ? s0 : (z == 1) ? s1 : (z == 2) ? s2 : s3;
  short* d = (z == 0) ? d0 : (z == 1) ? d1 : (z == 2) ? d2 : d3;
  const int n = (z < 2) ? n_big : n_small;
  int i = blockIdx.x * blockDim.x + threadIdx.x;
  if (i < n) {
    f32x4 v = reinterpret_cast<const f32x4*>(s)[i];
    short4v o;
    o[0] = bf16r(v[0]); o[1] = bf16r(v[1]); o[2] = bf16r(v[2]); o[3] = bf16r(v[3]);
    reinterpret_cast<short4v*>(d)[i] = o;
  }
}

// 3 activation tensors (query/key/value), same size, z selects
__global__ void k_cvta(const float* __restrict__ s0, short* __restrict__ d0,
                       const float* __restrict__ s1, short* __restrict__ d1,
                       const float* __restrict__ s2, short* __restrict__ d2, int n4) {
  const int z = blockIdx.z;
  const float* s = (z == 0) ? s0 : (z == 1) ? s1 : s2;
  short* d = (z == 0) ? d0 : (z == 1) ? d1 : d2;
  int i = blockIdx.x * blockDim.x + threadIdx.x;
  if (i < n4) {
    f32x4 v = reinterpret_cast<const f32x4*>(s)[i];
    short4v o;
    o[0] = bf16r(v[0]); o[1] = bf16r(v[1]); o[2] = bf16r(v[2]); o[3] = bf16r(v[3]);
    reinterpret_cast<short4v*>(d)[i] = o;
  }
}

// ---------------- GEMM: C(M,N) = (A(M,K)bf16 @ W(N,K)^T + bias) * alpha ----------------
// [R9 verbatim — green]
template<bool OUT_F32, bool DUAL>
__global__ __launch_bounds__(256) void k_gemm(
    const short* __restrict__ Aw, const short* __restrict__ Bw,
    const float* __restrict__ bias, void* __restrict__ Cp,
    const short* __restrict__ Aw2, const short* __restrict__ Bw2,
    const float* __restrict__ bias2, void* __restrict__ Cp2,
    int M, int N, int K, float alpha)
{
  if constexpr (DUAL) {
    if (blockIdx.z) { Aw = Aw2; Bw = Bw2; bias = bias2; Cp = Cp2; }
  }
  __shared__ short As[2][128 * 64];
  __shared__ short Bs[2][128 * 64];
  const int t = threadIdx.x;
  const int lane = t & 63;
  const int wid = t >> 6;
  const int wr = wid >> 1, wc = wid & 1;
  const int bm = blockIdx.y * 128;
  const int bn = blockIdx.x * 128;

  f32x4 acc[4][4];
  #pragma unroll
  for (int i = 0; i < 4; ++i)
    #pragma unroll
    for (int j = 0; j < 4; ++j) acc[i][j] = f32x4{0.f, 0.f, 0.f, 0.f};

  const int nt = K >> 6;

  auto stage = [&](const short* G, short (&buf)[128 * 64], int k0) {
    #pragma unroll
    for (int i = 0; i < 4; ++i) {
      int lin = t * 16 + i * 4096;
      int a = lin ^ (((lin >> 7) & 7) << 4);
      int row = a >> 7;
      int col = (a & 127) >> 1;
      const short* g = G + (size_t)row * K + k0 + col;
      gload_lds16(g, (char*)(&buf[0]) + (wid << 10) + (i << 12));
    }
  };

  stage(Aw + (size_t)bm * K, As[0], 0);
  stage(Bw + (size_t)bn * K, Bs[0], 0);
  __syncthreads();

  int cur = 0;
  for (int kt = 0; kt < nt; ++kt) {
    const bool pf = (kt + 1 < nt);
    if (pf) {
      stage(Aw + (size_t)bm * K, As[cur ^ 1], (kt + 1) << 6);
      stage(Bw + (size_t)bn * K, Bs[cur ^ 1], (kt + 1) << 6);
    }
    #pragma unroll
    for (int kk = 0; kk < 2; ++kk) {
      const int kb = (kk * 32 + ((lane >> 4) << 3)) << 1;
      short8 af[4], bfr[4];
      #pragma unroll
      for (int i = 0; i < 4; ++i) {
        int row = wr * 64 + i * 16 + (lane & 15);
        int byte = ((row << 7) + kb) ^ ((row & 7) << 4);
        af[i] = *reinterpret_cast<const short8*>((const char*)(&As[cur][0]) + byte);
      }
      #pragma unroll
      for (int j = 0; j < 4; ++j) {
        int row = wc * 64 + j * 16 + (lane & 15);
        int byte = ((row << 7) + kb) ^ ((row & 7) << 4);
        bfr[j] = *reinterpret_cast<const short8*>((const char*)(&Bs[cur][0]) + byte);
      }
      __builtin_amdgcn_s_setprio(1);
      #pragma unroll
      for (int i = 0; i < 4; ++i)
        #pragma unroll
        for (int j = 0; j < 4; ++j)
          acc[i][j] = mfma16(af[i], bfr[j], acc[i][j]);
      __builtin_amdgcn_s_setprio(0);
    }
    __syncthreads();
    cur ^= 1;
  }

  #pragma unroll
  for (int j = 0; j < 4; ++j) {
    int col = bn + wc * 64 + j * 16 + (lane & 15);
    float bv = bias[col];
    #pragma unroll
    for (int i = 0; i < 4; ++i) {
      int row0 = bm + wr * 64 + i * 16 + ((lane >> 4) << 2);
      #pragma unroll
      for (int r = 0; r < 4; ++r) {
        float v = (acc[i][j][r] + bv) * alpha;
        if constexpr (OUT_F32)
          ((float*)Cp)[(size_t)(row0 + r) * N + col] = v;
        else
          ((short*)Cp)[(size_t)(row0 + r) * N + col] = bf16r(v);
      }
    }
  }
}

// ---------------- flash attention, 8-warp swapped-QK^T (R9 structure — green) ----------------
// Changes vs R9 (both latency-only, no new live state):
//  (1) tree max/sum reductions (serial 32-chain -> depth-5; fp reorder only)
//  (2) s_setprio(1) around QK^T and PV MFMA clusters (T5, +4-7% attn per m191)
// NOTE: fixed-m=0 softmax in this structure fails (R5-R7, ~0.04) — keep defer-max.
// NOTE: S-ahead pipeline (R10) spills (scratch traffic +11MB) — do not re-add.
__global__ __launch_bounds__(512) void k_attn(
    const short* __restrict__ Q, const short* __restrict__ Kg,
    const short* __restrict__ Vg, short* __restrict__ Op)
{
  constexpr int T = 2048;
  constexpr int NT = T / 64;

  // bijective XCD-chunked swizzle: 512 blocks -> 64 contiguous per XCD
  const int orig = blockIdx.x;
  const int wgid = (orig & 7) * 64 + (orig >> 3);
  const int bh = wgid >> 3;            // 0..63 = b*32+h
  const int qb = wgid & 7;
  const int b = bh >> 5, h = bh & 31;
  const int g = h >> 2;
  const int q0 = qb * 256;

  const int t = threadIdx.x;
  const int lane = t & 63;
  const int wid = t >> 6;
  const int lo = lane & 31;
  const int hi = lane >> 5;

  __shared__ alignas(16) union {
    struct {
      short Kl[2][64 * 64];   // [key][d], XOR-swizzled bytes, gload_lds staged
      short Vt[2][64 * 72];   // [d][key], stride 72, reg-staged transpose
    } s;
    short Ol[8][32 * 72];     // epilogue O transpose, per-warp
  } sm;

  const size_t qrow = (size_t)(b * T + q0 + wid * 32 + lo);
  short8 qf[4];
  #pragma unroll
  for (int s = 0; s < 4; ++s)
    qf[s] = *reinterpret_cast<const short8*>(Q + qrow * 2048 + h * 64 + s * 16 + hi * 8);

  f32x16 o0, o1;
  #pragma unroll
  for (int r = 0; r < 16; ++r) { o0[r] = 0.f; o1[r] = 0.f; }
  float m = -10000.f, l = 0.f;

  const short* Kbase = Kg + (size_t)(b * T) * 512 + g * 64;
  const short* Vbase = Vg + (size_t)(b * T) * 512 + g * 64;

  auto stageK = [&](int buf, int k0) {
    int lin = t * 16;                            // linear LDS byte dest
    int a = lin ^ (((lin >> 7) & 7) << 4);       // inverse-swizzled logical src
    int row = a >> 7;
    int col = (a & 127) >> 1;
    gload_lds16(Kbase + (size_t)(k0 + row) * 512 + col,
                (char*)(&sm.s.Kl[buf][0]) + (wid << 10));
  };
  short8 vreg;
  auto loadV = [&](int k0) {
    vreg = *reinterpret_cast<const short8*>(
        Vbase + (size_t)(k0 + lane) * 512 + wid * 8);
  };
  auto writeV = [&](int buf) {
    #pragma unroll
    for (int e = 0; e < 8; ++e)
      sm.s.Vt[buf][(wid * 8 + e) * 72 + lane] = vreg[e];
  };

  stageK(0, 0);
  loadV(0);
  writeV(0);
  __syncthreads();

  int cur = 0;
  for (int kt = 0; kt < NT; ++kt) {
    const bool pf = (kt + 1 < NT);
    if (pf) { stageK(cur ^ 1, (kt + 1) * 64); loadV((kt + 1) * 64); }

    // ---- K frags (A-operand) + QK^T ----
    short8 kf[2][4];
    #pragma unroll
    for (int tt = 0; tt < 2; ++tt)
      #pragma unroll
      for (int s = 0; s < 4; ++s) {
        int row = tt * 32 + lo;
        int byte = ((row << 7) + (s << 5) + (hi << 4)) ^ ((row & 7) << 4);
        kf[tt][s] = *reinterpret_cast<const short8*>((const char*)(&sm.s.Kl[cur][0]) + byte);
      }
    f32x16 st0, st1;
    #pragma unroll
    for (int r = 0; r < 16; ++r) { st0[r] = 0.f; st1[r] = 0.f; }
    __builtin_amdgcn_s_setprio(1);
    #pragma unroll
    for (int s = 0; s < 4; ++s) {
      st0 = mfma32(kf[0][s], qf[s], st0);
      st1 = mfma32(kf[1][s], qf[s], st1);
    }
    __builtin_amdgcn_s_setprio(0);

    // ---- online softmax (log2 domain), lane-local q; tree reductions ----
    float mx = fmaxf(max16(st0), max16(st1));
    mx = fmaxf(mx, __shfl_xor(mx, 32));
    if (!__all(mx - m <= 8.0f)) {      // T13 defer-max
      float mn = fmaxf(m, mx);
      float sc = fexp2(m - mn);
      m = mn; l *= sc;
      o0 = o0 * sc; o1 = o1 * sc;
    }
    #pragma unroll
    for (int r = 0; r < 16; ++r) st0[r] = fexp2(st0[r] - m);
    #pragma unroll
    for (int r = 0; r < 16; ++r) st1[r] = fexp2(st1[r] - m);
    float ssum = sum16(st0) + sum16(st1);
    ssum += __shfl_xor(ssum, 32);
    l += ssum;

    // ---- P -> bf16 B-frags: cvt_pk + cross-half shfl_xor redistribution ----
    short8 pb[4];
    #pragma unroll
    for (int tt = 0; tt < 2; ++tt) {
      const f32x16& sv = tt ? st1 : st0;
      #pragma unroll
      for (int half = 0; half < 2; ++half) {
        unsigned x1 = cvtpk(sv[half * 8 + 0], sv[half * 8 + 1]);
        unsigned x2 = cvtpk(sv[half * 8 + 2], sv[half * 8 + 3]);
        unsigned x3 = cvtpk(sv[half * 8 + 4], sv[half * 8 + 5]);
        unsigned x4 = cvtpk(sv[half * 8 + 6], sv[half * 8 + 7]);
        unsigned y1 = __shfl_xor(x1, 32);
        unsigned y2 = __shfl_xor(x2, 32);
        unsigned y3 = __shfl_xor(x3, 32);
        unsigned y4 = __shfl_xor(x4, 32);
        union { unsigned u[4]; short8 s8; } p;
        p.u[0] = hi ? y3 : x1;
        p.u[1] = hi ? y4 : x2;
        p.u[2] = hi ? x3 : y1;
        p.u[3] = hi ? x4 : y2;
        pb[tt * 2 + half] = p.s8;
      }
    }

    // ---- V^T frags (A-operand) + PV ----
    __builtin_amdgcn_s_setprio(1);
    #pragma unroll
    for (int ks = 0; ks < 4; ++ks) {
      {
        int byte = (lo * 144) + (ks << 5) + (hi << 4);
        short8 va = *reinterpret_cast<const short8*>((const char*)(&sm.s.Vt[cur][0]) + byte);
        o0 = mfma32(va, pb[ks], o0);
      }
      {
        int byte = ((32 + lo) * 144) + (ks << 5) + (hi << 4);
        short8 va = *reinterpret_cast<const short8*>((const char*)(&sm.s.Vt[cur][0]) + byte);
        o1 = mfma32(va, pb[ks], o1);
      }
    }
    __builtin_amdgcn_s_setprio(0);

    if (pf) writeV(cur ^ 1);
    __syncthreads();
    cur ^= 1;
  }

  // ---- epilogue: normalize, transpose via LDS, coalesced store ----
  float inv = 1.0f / l;
  #pragma unroll
  for (int dt = 0; dt < 2; ++dt) {
    const f32x16& ov = dt ? o1 : o0;
    #pragma unroll
    for (int r = 0; r < 16; r += 2) {
      unsigned d2 = cvtpk(ov[r] * inv, ov[r + 1] * inv);
      int dpos = dt * 32 + (r & 3) + 8 * (r >> 2) + 4 * hi;
      *reinterpret_cast<unsigned*>((char*)(&sm.Ol[wid][0]) + (lo * 72 + dpos) * 2) = d2;
    }
  }
  __syncthreads();
  #pragma unroll
  for (int i = 0; i < 4; ++i) {
    int c = hi * 4 + i;
    short8 v = *reinterpret_cast<const short8*>((const char*)(&sm.Ol[wid][0]) + lo * 144 + c * 16);
    *reinterpret_cast<short8*>(Op + qrow * 2048 + h * 64 + c * 8) = v;
  }
}

// ---------------- launch ----------------
// Workspace (62914560 B):
//   [0..8M) q_wb  [8M..10M) k_wb  [10M..12M) v_wb  [12M..20M) o_wb
//   R1 [20M..36M): kx -> Ap (attn out)
//   R2 [36M..52M): vx
//   [52M..56M) Kp   [56M..60M) Vp
// d_out (33.5 MB fp32 out) doubles as scratch BEFORE O-proj:
//   qx = d_out[0..16M) bf16, Qp = d_out[16M..32M) bf16 — O-proj fully overwrites.
extern "C" void kernel_launch(void* const* d_in, const int* in_sizes, int n_in,
                              void* d_out, int out_size, void* d_ws, size_t ws_size,
                              hipStream_t stream)
{
  const float* query = (const float*)d_in[0];
  const float* key   = (const float*)d_in[1];
  const float* value = (const float*)d_in[2];
  const float* q_w   = (const float*)d_in[3];
  const float* q_b   = (const float*)d_in[4];
  const float* k_w   = (const float*)d_in[5];
  const float* k_b   = (const float*)d_in[6];
  const float* v_w   = (const float*)d_in[7];
  const float* v_b   = (const float*)d_in[8];
  const float* o_w   = (const float*)d_in[9];
  const float* o_b   = (const float*)d_in[10];
  float* out = (float*)d_out;

  char* ws = (char*)d_ws;
  short* q_wb = (short*)(ws);
  short* k_wb = (short*)(ws + 8388608);
  short* v_wb = (short*)(ws + 10485760);
  short* o_wb = (short*)(ws + 12582912);
  short* R1   = (short*)(ws + 20971520);   // kx -> Ap
  short* R2   = (short*)(ws + 37748736);   // vx
  short* Kp   = (short*)(ws + 54525952);
  short* Vp   = (short*)(ws + 58720256);

  short* qx = (short*)d_out;                       // 16777216 B
  short* Qp = (short*)((char*)d_out + 16777216);   // 16777216 B

  const float ALPHA_Q = 0.125f * 1.4426950408889634f;  // SCALE * log2(e)

  // all 4 weight cvts in one dispatch; all 3 activation cvts in one dispatch
  k_cvtw<<<dim3(4096, 1, 4), 256, 0, stream>>>(
      q_w, q_wb, o_w, o_wb, k_w, k_wb, v_w, v_wb, 1048576, 262144);
  k_cvta<<<dim3(8192, 1, 3), 256, 0, stream>>>(
      query, qx, key, R1, value, R2, 2097152);

  // Q-proj (qx@d_out -> Qp@d_out) — no longer waits on KV-proj
  k_gemm<false, false><<<dim3(16, 32), 256, 0, stream>>>(
      qx, q_wb, q_b, Qp, nullptr, nullptr, nullptr, nullptr, 4096, 2048, 2048, ALPHA_Q);

  // fused K-proj / V-proj (R1,R2 -> Kp,Vp)
  k_gemm<false, true><<<dim3(4, 32, 2), 256, 0, stream>>>(
      R1, k_wb, k_b, Kp, R2, v_wb, v_b, Vp, 4096, 512, 2048, 1.0f);

  // attention (Qp@d_out, Kp, Vp -> Ap@R1; kx dead)
  k_attn<<<dim3(512), dim3(512), 0, stream>>>(Qp, Kp, Vp, R1);

  // O-proj (Ap@R1 -> out; overwrites ALL of d_out)
  k_gemm<true, false><<<dim3(16, 32), 256, 0, stream>>>(
      R1, o_wb, o_b, out, nullptr, nullptr, nullptr, nullptr, 4096, 2048, 2048, 1.0f);
}

// Round 12
// 264.228 us; speedup vs baseline: 1.0284x; 1.0284x over previous
//
#include <hip/hip_runtime.h>
#include <stdint.h>
#include <stddef.h>

using short8 = __attribute__((ext_vector_type(8))) short;
using short4v = __attribute__((ext_vector_type(4))) short;
using f32x4  = __attribute__((ext_vector_type(4))) float;
using f32x16 = __attribute__((ext_vector_type(16))) float;
using bf16x8 = __attribute__((ext_vector_type(8))) __bf16;

#define DEVI __device__ __forceinline__

// round-to-nearest-even fp32 -> bf16 (bit pattern as short)
DEVI short bf16r(float f) {
  union { float f; uint32_t u; } x; x.f = f;
  uint32_t r = x.u + 0x7FFFu + ((x.u >> 16) & 1u);
  return (short)(r >> 16);
}

DEVI f32x4 mfma16(short8 a, short8 b, f32x4 c) {
  return __builtin_amdgcn_mfma_f32_16x16x32_bf16(
      __builtin_bit_cast(bf16x8, a), __builtin_bit_cast(bf16x8, b), c, 0, 0, 0);
}

DEVI f32x16 mfma32(short8 a, short8 b, f32x16 c) {
  return __builtin_amdgcn_mfma_f32_32x32x16_bf16(
      __builtin_bit_cast(bf16x8, a), __builtin_bit_cast(bf16x8, b), c, 0, 0, 0);
}

DEVI void gload_lds16(const void* g, void* l) {
  __builtin_amdgcn_global_load_lds(
      (const void __attribute__((address_space(1)))*)g,
      (void __attribute__((address_space(3)))*)l,
      16, 0, 0);
}

// v_exp_f32 computes 2^x
DEVI float fexp2(float x) {
  float r;
  asm("v_exp_f32 %0, %1" : "=v"(r) : "v"(x));
  return r;
}

// packed fp32->bf16: dst[15:0]=bf16(a), dst[31:16]=bf16(b)
DEVI unsigned cvtpk(float a, float b) {
  unsigned r;
  asm("v_cvt_pk_bf16_f32 %0, %1, %2" : "=v"(r) : "v"(a), "v"(b));
  return r;
}

// pairwise-tree reductions (short dependency chains; fp reorder only)
DEVI float max16(const f32x16& v) {
  float a = fmaxf(fmaxf(v[0], v[1]), fmaxf(v[2], v[3]));
  float b = fmaxf(fmaxf(v[4], v[5]), fmaxf(v[6], v[7]));
  float c = fmaxf(fmaxf(v[8], v[9]), fmaxf(v[10], v[11]));
  float d = fmaxf(fmaxf(v[12], v[13]), fmaxf(v[14], v[15]));
  return fmaxf(fmaxf(a, b), fmaxf(c, d));
}
DEVI float sum16(const f32x16& v) {
  float a = (v[0] + v[1]) + (v[2] + v[3]);
  float b = (v[4] + v[5]) + (v[6] + v[7]);
  float c = (v[8] + v[9]) + (v[10] + v[11]);
  float d = (v[12] + v[13]) + (v[14] + v[15]);
  return (a + b) + (c + d);
}

// ---------------- fp32 -> bf16 conversions ----------------
// 4 weight tensors in one dispatch: z in 0..3; z<2 big (n_big), z>=2 small (n_small)
__global__ void k_cvtw(const float* __restrict__ s0, short* __restrict__ d0,
                       const float* __restrict__ s1, short* __restrict__ d1,
                       const float* __restrict__ s2, short* __restrict__ d2,
                       const float* __restrict__ s3, short* __restrict__ d3,
                       int n_big, int n_small) {
  const int z = blockIdx.z;
  const float* s = (z == 0) ? s0 : (z == 1) ? s1 : (z == 2) ? s2 : s3;
  short* d = (z == 0) ? d0 : (z == 1) ? d1 : (z == 2) ? d2 : d3;
  const int n = (z < 2) ? n_big : n_small;
  int i = blockIdx.x * blockDim.x + threadIdx.x;
  if (i < n) {
    f32x4 v = reinterpret_cast<const f32x4*>(s)[i];
    short4v o;
    o[0] = bf16r(v[0]); o[1] = bf16r(v[1]); o[2] = bf16r(v[2]); o[3] = bf16r(v[3]);
    reinterpret_cast<short4v*>(d)[i] = o;
  }
}

// 3 activation tensors (query/key/value), same size, z selects
__global__ void k_cvta(const float* __restrict__ s0, short* __restrict__ d0,
                       const float* __restrict__ s1, short* __restrict__ d1,
                       const float* __restrict__ s2, short* __restrict__ d2, int n4) {
  const int z = blockIdx.z;
  const float* s = (z == 0) ? s0 : (z == 1) ? s1 : s2;
  short* d = (z == 0) ? d0 : (z == 1) ? d1 : d2;
  int i = blockIdx.x * blockDim.x + threadIdx.x;
  if (i < n4) {
    f32x4 v = reinterpret_cast<const f32x4*>(s)[i];
    short4v o;
    o[0] = bf16r(v[0]); o[1] = bf16r(v[1]); o[2] = bf16r(v[2]); o[3] = bf16r(v[3]);
    reinterpret_cast<short4v*>(d)[i] = o;
  }
}

// ---------------- GEMM: C(M,N) = (A(M,K)bf16 @ W(N,K)^T + bias) * alpha ----------------
// [R9 verbatim — green]
template<bool OUT_F32, bool DUAL>
__global__ __launch_bounds__(256) void k_gemm(
    const short* __restrict__ Aw, const short* __restrict__ Bw,
    const float* __restrict__ bias, void* __restrict__ Cp,
    const short* __restrict__ Aw2, const short* __restrict__ Bw2,
    const float* __restrict__ bias2, void* __restrict__ Cp2,
    int M, int N, int K, float alpha)
{
  if constexpr (DUAL) {
    if (blockIdx.z) { Aw = Aw2; Bw = Bw2; bias = bias2; Cp = Cp2; }
  }
  __shared__ short As[2][128 * 64];
  __shared__ short Bs[2][128 * 64];
  const int t = threadIdx.x;
  const int lane = t & 63;
  const int wid = t >> 6;
  const int wr = wid >> 1, wc = wid & 1;
  const int bm = blockIdx.y * 128;
  const int bn = blockIdx.x * 128;

  f32x4 acc[4][4];
  #pragma unroll
  for (int i = 0; i < 4; ++i)
    #pragma unroll
    for (int j = 0; j < 4; ++j) acc[i][j] = f32x4{0.f, 0.f, 0.f, 0.f};

  const int nt = K >> 6;

  auto stage = [&](const short* G, short (&buf)[128 * 64], int k0) {
    #pragma unroll
    for (int i = 0; i < 4; ++i) {
      int lin = t * 16 + i * 4096;
      int a = lin ^ (((lin >> 7) & 7) << 4);
      int row = a >> 7;
      int col = (a & 127) >> 1;
      const short* g = G + (size_t)row * K + k0 + col;
      gload_lds16(g, (char*)(&buf[0]) + (wid << 10) + (i << 12));
    }
  };

  stage(Aw + (size_t)bm * K, As[0], 0);
  stage(Bw + (size_t)bn * K, Bs[0], 0);
  __syncthreads();

  int cur = 0;
  for (int kt = 0; kt < nt; ++kt) {
    const bool pf = (kt + 1 < nt);
    if (pf) {
      stage(Aw + (size_t)bm * K, As[cur ^ 1], (kt + 1) << 6);
      stage(Bw + (size_t)bn * K, Bs[cur ^ 1], (kt + 1) << 6);
    }
    #pragma unroll
    for (int kk = 0; kk < 2; ++kk) {
      const int kb = (kk * 32 + ((lane >> 4) << 3)) << 1;
      short8 af[4], bfr[4];
      #pragma unroll
      for (int i = 0; i < 4; ++i) {
        int row = wr * 64 + i * 16 + (lane & 15);
        int byte = ((row << 7) + kb) ^ ((row & 7) << 4);
        af[i] = *reinterpret_cast<const short8*>((const char*)(&As[cur][0]) + byte);
      }
      #pragma unroll
      for (int j = 0; j < 4; ++j) {
        int row = wc * 64 + j * 16 + (lane & 15);
        int byte = ((row << 7) + kb) ^ ((row & 7) << 4);
        bfr[j] = *reinterpret_cast<const short8*>((const char*)(&Bs[cur][0]) + byte);
      }
      __builtin_amdgcn_s_setprio(1);
      #pragma unroll
      for (int i = 0; i < 4; ++i)
        #pragma unroll
        for (int j = 0; j < 4; ++j)
          acc[i][j] = mfma16(af[i], bfr[j], acc[i][j]);
      __builtin_amdgcn_s_setprio(0);
    }
    __syncthreads();
    cur ^= 1;
  }

  #pragma unroll
  for (int j = 0; j < 4; ++j) {
    int col = bn + wc * 64 + j * 16 + (lane & 15);
    float bv = bias[col];
    #pragma unroll
    for (int i = 0; i < 4; ++i) {
      int row0 = bm + wr * 64 + i * 16 + ((lane >> 4) << 2);
      #pragma unroll
      for (int r = 0; r < 4; ++r) {
        float v = (acc[i][j][r] + bv) * alpha;
        if constexpr (OUT_F32)
          ((float*)Cp)[(size_t)(row0 + r) * N + col] = v;
        else
          ((short*)Cp)[(size_t)(row0 + r) * N + col] = bf16r(v);
      }
    }
  }
}

// ---------------- flash attention, 8-warp swapped-QK^T (R9 structure — green) ----------------
// Change vs R9: tree max/sum reductions ONLY (fp reorder, depth 32->5).
// NO setprio in this kernel: R11 A/B showed setprio in this barrier-lockstep
// structure costs ~25 µs (occupancy 35->21%) — consistent with m190/m224
// (T5 pays only with phase-split wave role diversity; lockstep = negative).
// NOTE: fixed-m=0 softmax in this structure fails (R5-R7, ~0.04) — keep defer-max.
// NOTE: S-ahead pipeline (R10) spills (scratch +11MB) — do not re-add.
__global__ __launch_bounds__(512) void k_attn(
    const short* __restrict__ Q, const short* __restrict__ Kg,
    const short* __restrict__ Vg, short* __restrict__ Op)
{
  constexpr int T = 2048;
  constexpr int NT = T / 64;

  // bijective XCD-chunked swizzle: 512 blocks -> 64 contiguous per XCD
  const int orig = blockIdx.x;
  const int wgid = (orig & 7) * 64 + (orig >> 3);
  const int bh = wgid >> 3;            // 0..63 = b*32+h
  const int qb = wgid & 7;
  const int b = bh >> 5, h = bh & 31;
  const int g = h >> 2;
  const int q0 = qb * 256;

  const int t = threadIdx.x;
  const int lane = t & 63;
  const int wid = t >> 6;
  const int lo = lane & 31;
  const int hi = lane >> 5;

  __shared__ alignas(16) union {
    struct {
      short Kl[2][64 * 64];   // [key][d], XOR-swizzled bytes, gload_lds staged
      short Vt[2][64 * 72];   // [d][key], stride 72, reg-staged transpose
    } s;
    short Ol[8][32 * 72];     // epilogue O transpose, per-warp
  } sm;

  const size_t qrow = (size_t)(b * T + q0 + wid * 32 + lo);
  short8 qf[4];
  #pragma unroll
  for (int s = 0; s < 4; ++s)
    qf[s] = *reinterpret_cast<const short8*>(Q + qrow * 2048 + h * 64 + s * 16 + hi * 8);

  f32x16 o0, o1;
  #pragma unroll
  for (int r = 0; r < 16; ++r) { o0[r] = 0.f; o1[r] = 0.f; }
  float m = -10000.f, l = 0.f;

  const short* Kbase = Kg + (size_t)(b * T) * 512 + g * 64;
  const short* Vbase = Vg + (size_t)(b * T) * 512 + g * 64;

  auto stageK = [&](int buf, int k0) {
    int lin = t * 16;                            // linear LDS byte dest
    int a = lin ^ (((lin >> 7) & 7) << 4);       // inverse-swizzled logical src
    int row = a >> 7;
    int col = (a & 127) >> 1;
    gload_lds16(Kbase + (size_t)(k0 + row) * 512 + col,
                (char*)(&sm.s.Kl[buf][0]) + (wid << 10));
  };
  short8 vreg;
  auto loadV = [&](int k0) {
    vreg = *reinterpret_cast<const short8*>(
        Vbase + (size_t)(k0 + lane) * 512 + wid * 8);
  };
  auto writeV = [&](int buf) {
    #pragma unroll
    for (int e = 0; e < 8; ++e)
      sm.s.Vt[buf][(wid * 8 + e) * 72 + lane] = vreg[e];
  };

  stageK(0, 0);
  loadV(0);
  writeV(0);
  __syncthreads();

  int cur = 0;
  for (int kt = 0; kt < NT; ++kt) {
    const bool pf = (kt + 1 < NT);
    if (pf) { stageK(cur ^ 1, (kt + 1) * 64); loadV((kt + 1) * 64); }

    // ---- K frags (A-operand) + QK^T ----
    short8 kf[2][4];
    #pragma unroll
    for (int tt = 0; tt < 2; ++tt)
      #pragma unroll
      for (int s = 0; s < 4; ++s) {
        int row = tt * 32 + lo;
        int byte = ((row << 7) + (s << 5) + (hi << 4)) ^ ((row & 7) << 4);
        kf[tt][s] = *reinterpret_cast<const short8*>((const char*)(&sm.s.Kl[cur][0]) + byte);
      }
    f32x16 st0, st1;
    #pragma unroll
    for (int r = 0; r < 16; ++r) { st0[r] = 0.f; st1[r] = 0.f; }
    #pragma unroll
    for (int s = 0; s < 4; ++s) {
      st0 = mfma32(kf[0][s], qf[s], st0);
      st1 = mfma32(kf[1][s], qf[s], st1);
    }

    // ---- online softmax (log2 domain), lane-local q; tree reductions ----
    float mx = fmaxf(max16(st0), max16(st1));
    mx = fmaxf(mx, __shfl_xor(mx, 32));
    if (!__all(mx - m <= 8.0f)) {      // T13 defer-max
      float mn = fmaxf(m, mx);
      float sc = fexp2(m - mn);
      m = mn; l *= sc;
      o0 = o0 * sc; o1 = o1 * sc;
    }
    #pragma unroll
    for (int r = 0; r < 16; ++r) st0[r] = fexp2(st0[r] - m);
    #pragma unroll
    for (int r = 0; r < 16; ++r) st1[r] = fexp2(st1[r] - m);
    float ssum = sum16(st0) + sum16(st1);
    ssum += __shfl_xor(ssum, 32);
    l += ssum;

    // ---- P -> bf16 B-frags: cvt_pk + cross-half shfl_xor redistribution ----
    short8 pb[4];
    #pragma unroll
    for (int tt = 0; tt < 2; ++tt) {
      const f32x16& sv = tt ? st1 : st0;
      #pragma unroll
      for (int half = 0; half < 2; ++half) {
        unsigned x1 = cvtpk(sv[half * 8 + 0], sv[half * 8 + 1]);
        unsigned x2 = cvtpk(sv[half * 8 + 2], sv[half * 8 + 3]);
        unsigned x3 = cvtpk(sv[half * 8 + 4], sv[half * 8 + 5]);
        unsigned x4 = cvtpk(sv[half * 8 + 6], sv[half * 8 + 7]);
        unsigned y1 = __shfl_xor(x1, 32);
        unsigned y2 = __shfl_xor(x2, 32);
        unsigned y3 = __shfl_xor(x3, 32);
        unsigned y4 = __shfl_xor(x4, 32);
        union { unsigned u[4]; short8 s8; } p;
        p.u[0] = hi ? y3 : x1;
        p.u[1] = hi ? y4 : x2;
        p.u[2] = hi ? x3 : y1;
        p.u[3] = hi ? x4 : y2;
        pb[tt * 2 + half] = p.s8;
      }
    }

    // ---- V^T frags (A-operand) + PV ----
    #pragma unroll
    for (int ks = 0; ks < 4; ++ks) {
      {
        int byte = (lo * 144) + (ks << 5) + (hi << 4);
        short8 va = *reinterpret_cast<const short8*>((const char*)(&sm.s.Vt[cur][0]) + byte);
        o0 = mfma32(va, pb[ks], o0);
      }
      {
        int byte = ((32 + lo) * 144) + (ks << 5) + (hi << 4);
        short8 va = *reinterpret_cast<const short8*>((const char*)(&sm.s.Vt[cur][0]) + byte);
        o1 = mfma32(va, pb[ks], o1);
      }
    }

    if (pf) writeV(cur ^ 1);
    __syncthreads();
    cur ^= 1;
  }

  // ---- epilogue: normalize, transpose via LDS, coalesced store ----
  float inv = 1.0f / l;
  #pragma unroll
  for (int dt = 0; dt < 2; ++dt) {
    const f32x16& ov = dt ? o1 : o0;
    #pragma unroll
    for (int r = 0; r < 16; r += 2) {
      unsigned d2 = cvtpk(ov[r] * inv, ov[r + 1] * inv);
      int dpos = dt * 32 + (r & 3) + 8 * (r >> 2) + 4 * hi;
      *reinterpret_cast<unsigned*>((char*)(&sm.Ol[wid][0]) + (lo * 72 + dpos) * 2) = d2;
    }
  }
  __syncthreads();
  #pragma unroll
  for (int i = 0; i < 4; ++i) {
    int c = hi * 4 + i;
    short8 v = *reinterpret_cast<const short8*>((const char*)(&sm.Ol[wid][0]) + lo * 144 + c * 16);
    *reinterpret_cast<short8*>(Op + qrow * 2048 + h * 64 + c * 8) = v;
  }
}

// ---------------- launch (R11's validated dataflow) ----------------
// Workspace (62914560 B):
//   [0..8M) q_wb  [8M..10M) k_wb  [10M..12M) v_wb  [12M..20M) o_wb
//   R1 [20M..36M): kx -> Ap (attn out)
//   R2 [36M..52M): vx
//   [52M..56M) Kp   [56M..60M) Vp
// d_out (33.5 MB fp32 out) doubles as scratch BEFORE O-proj:
//   qx = d_out[0..16M) bf16, Qp = d_out[16M..32M) bf16 — O-proj fully overwrites.
extern "C" void kernel_launch(void* const* d_in, const int* in_sizes, int n_in,
                              void* d_out, int out_size, void* d_ws, size_t ws_size,
                              hipStream_t stream)
{
  const float* query = (const float*)d_in[0];
  const float* key   = (const float*)d_in[1];
  const float* value = (const float*)d_in[2];
  const float* q_w   = (const float*)d_in[3];
  const float* q_b   = (const float*)d_in[4];
  const float* k_w   = (const float*)d_in[5];
  const float* k_b   = (const float*)d_in[6];
  const float* v_w   = (const float*)d_in[7];
  const float* v_b   = (const float*)d_in[8];
  const float* o_w   = (const float*)d_in[9];
  const float* o_b   = (const float*)d_in[10];
  float* out = (float*)d_out;

  char* ws = (char*)d_ws;
  short* q_wb = (short*)(ws);
  short* k_wb = (short*)(ws + 8388608);
  short* v_wb = (short*)(ws + 10485760);
  short* o_wb = (short*)(ws + 12582912);
  short* R1   = (short*)(ws + 20971520);   // kx -> Ap
  short* R2   = (short*)(ws + 37748736);   // vx
  short* Kp   = (short*)(ws + 54525952);
  short* Vp   = (short*)(ws + 58720256);

  short* qx = (short*)d_out;                       // 16777216 B
  short* Qp = (short*)((char*)d_out + 16777216);   // 16777216 B

  const float ALPHA_Q = 0.125f * 1.4426950408889634f;  // SCALE * log2(e)

  // all 4 weight cvts in one dispatch; all 3 activation cvts in one dispatch
  k_cvtw<<<dim3(4096, 1, 4), 256, 0, stream>>>(
      q_w, q_wb, o_w, o_wb, k_w, k_wb, v_w, v_wb, 1048576, 262144);
  k_cvta<<<dim3(8192, 1, 3), 256, 0, stream>>>(
      query, qx, key, R1, value, R2, 2097152);

  // Q-proj (qx@d_out -> Qp@d_out)
  k_gemm<false, false><<<dim3(16, 32), 256, 0, stream>>>(
      qx, q_wb, q_b, Qp, nullptr, nullptr, nullptr, nullptr, 4096, 2048, 2048, ALPHA_Q);

  // fused K-proj / V-proj (R1,R2 -> Kp,Vp)
  k_gemm<false, true><<<dim3(4, 32, 2), 256, 0, stream>>>(
      R1, k_wb, k_b, Kp, R2, v_wb, v_b, Vp, 4096, 512, 2048, 1.0f);

  // attention (Qp@d_out, Kp, Vp -> Ap@R1; kx dead)
  k_attn<<<dim3(512), dim3(512), 0, stream>>>(Qp, Kp, Vp, R1);

  // O-proj (Ap@R1 -> out; overwrites ALL of d_out)
  k_gemm<true, false><<<dim3(16, 32), 256, 0, stream>>>(
      R1, o_wb, o_b, out, nullptr, nullptr, nullptr, nullptr, 4096, 2048, 2048, 1.0f);
}

// Round 13
// 253.051 us; speedup vs baseline: 1.0739x; 1.0442x over previous
//
#include <hip/hip_runtime.h>
#include <stdint.h>
#include <stddef.h>

using short8 = __attribute__((ext_vector_type(8))) short;
using short4v = __attribute__((ext_vector_type(4))) short;
using f32x4  = __attribute__((ext_vector_type(4))) float;
using f32x16 = __attribute__((ext_vector_type(16))) float;
using bf16x8 = __attribute__((ext_vector_type(8))) __bf16;

#define DEVI __device__ __forceinline__

// round-to-nearest-even fp32 -> bf16 (bit pattern as short)
DEVI short bf16r(float f) {
  union { float f; uint32_t u; } x; x.f = f;
  uint32_t r = x.u + 0x7FFFu + ((x.u >> 16) & 1u);
  return (short)(r >> 16);
}

DEVI f32x4 mfma16(short8 a, short8 b, f32x4 c) {
  return __builtin_amdgcn_mfma_f32_16x16x32_bf16(
      __builtin_bit_cast(bf16x8, a), __builtin_bit_cast(bf16x8, b), c, 0, 0, 0);
}

DEVI f32x16 mfma32(short8 a, short8 b, f32x16 c) {
  return __builtin_amdgcn_mfma_f32_32x32x16_bf16(
      __builtin_bit_cast(bf16x8, a), __builtin_bit_cast(bf16x8, b), c, 0, 0, 0);
}

DEVI void gload_lds16(const void* g, void* l) {
  __builtin_amdgcn_global_load_lds(
      (const void __attribute__((address_space(1)))*)g,
      (void __attribute__((address_space(3)))*)l,
      16, 0, 0);
}

// v_exp_f32 computes 2^x
DEVI float fexp2(float x) {
  float r;
  asm("v_exp_f32 %0, %1" : "=v"(r) : "v"(x));
  return r;
}

// packed fp32->bf16: dst[15:0]=bf16(a), dst[31:16]=bf16(b)
DEVI unsigned cvtpk(float a, float b) {
  unsigned r;
  asm("v_cvt_pk_bf16_f32 %0, %1, %2" : "=v"(r) : "v"(a), "v"(b));
  return r;
}

// ---------------- fp32 -> bf16 conversions ----------------
// 4 weight tensors in one dispatch: z in 0..3; z<2 big (n_big), z>=2 small (n_small)
__global__ void k_cvtw(const float* __restrict__ s0, short* __restrict__ d0,
                       const float* __restrict__ s1, short* __restrict__ d1,
                       const float* __restrict__ s2, short* __restrict__ d2,
                       const float* __restrict__ s3, short* __restrict__ d3,
                       int n_big, int n_small) {
  const int z = blockIdx.z;
  const float* s = (z == 0) ? s0 : (z == 1) ? s1 : (z == 2) ? s2 : s3;
  short* d = (z == 0) ? d0 : (z == 1) ? d1 : (z == 2) ? d2 : d3;
  const int n = (z < 2) ? n_big : n_small;
  int i = blockIdx.x * blockDim.x + threadIdx.x;
  if (i < n) {
    f32x4 v = reinterpret_cast<const f32x4*>(s)[i];
    short4v o;
    o[0] = bf16r(v[0]); o[1] = bf16r(v[1]); o[2] = bf16r(v[2]); o[3] = bf16r(v[3]);
    reinterpret_cast<short4v*>(d)[i] = o;
  }
}

// 3 activation tensors (query/key/value), same size, z selects
__global__ void k_cvta(const float* __restrict__ s0, short* __restrict__ d0,
                       const float* __restrict__ s1, short* __restrict__ d1,
                       const float* __restrict__ s2, short* __restrict__ d2, int n4) {
  const int z = blockIdx.z;
  const float* s = (z == 0) ? s0 : (z == 1) ? s1 : s2;
  short* d = (z == 0) ? d0 : (z == 1) ? d1 : d2;
  int i = blockIdx.x * blockDim.x + threadIdx.x;
  if (i < n4) {
    f32x4 v = reinterpret_cast<const f32x4*>(s)[i];
    short4v o;
    o[0] = bf16r(v[0]); o[1] = bf16r(v[1]); o[2] = bf16r(v[2]); o[3] = bf16r(v[3]);
    reinterpret_cast<short4v*>(d)[i] = o;
  }
}

// ---------------- GEMM: C(M,N) = (A(M,K)bf16 @ W(N,K)^T + bias) * alpha ----------------
// [R9 verbatim — green]
template<bool OUT_F32, bool DUAL>
__global__ __launch_bounds__(256) void k_gemm(
    const short* __restrict__ Aw, const short* __restrict__ Bw,
    const float* __restrict__ bias, void* __restrict__ Cp,
    const short* __restrict__ Aw2, const short* __restrict__ Bw2,
    const float* __restrict__ bias2, void* __restrict__ Cp2,
    int M, int N, int K, float alpha)
{
  if constexpr (DUAL) {
    if (blockIdx.z) { Aw = Aw2; Bw = Bw2; bias = bias2; Cp = Cp2; }
  }
  __shared__ short As[2][128 * 64];
  __shared__ short Bs[2][128 * 64];
  const int t = threadIdx.x;
  const int lane = t & 63;
  const int wid = t >> 6;
  const int wr = wid >> 1, wc = wid & 1;
  const int bm = blockIdx.y * 128;
  const int bn = blockIdx.x * 128;

  f32x4 acc[4][4];
  #pragma unroll
  for (int i = 0; i < 4; ++i)
    #pragma unroll
    for (int j = 0; j < 4; ++j) acc[i][j] = f32x4{0.f, 0.f, 0.f, 0.f};

  const int nt = K >> 6;

  auto stage = [&](const short* G, short (&buf)[128 * 64], int k0) {
    #pragma unroll
    for (int i = 0; i < 4; ++i) {
      int lin = t * 16 + i * 4096;
      int a = lin ^ (((lin >> 7) & 7) << 4);
      int row = a >> 7;
      int col = (a & 127) >> 1;
      const short* g = G + (size_t)row * K + k0 + col;
      gload_lds16(g, (char*)(&buf[0]) + (wid << 10) + (i << 12));
    }
  };

  stage(Aw + (size_t)bm * K, As[0], 0);
  stage(Bw + (size_t)bn * K, Bs[0], 0);
  __syncthreads();

  int cur = 0;
  for (int kt = 0; kt < nt; ++kt) {
    const bool pf = (kt + 1 < nt);
    if (pf) {
      stage(Aw + (size_t)bm * K, As[cur ^ 1], (kt + 1) << 6);
      stage(Bw + (size_t)bn * K, Bs[cur ^ 1], (kt + 1) << 6);
    }
    #pragma unroll
    for (int kk = 0; kk < 2; ++kk) {
      const int kb = (kk * 32 + ((lane >> 4) << 3)) << 1;
      short8 af[4], bfr[4];
      #pragma unroll
      for (int i = 0; i < 4; ++i) {
        int row = wr * 64 + i * 16 + (lane & 15);
        int byte = ((row << 7) + kb) ^ ((row & 7) << 4);
        af[i] = *reinterpret_cast<const short8*>((const char*)(&As[cur][0]) + byte);
      }
      #pragma unroll
      for (int j = 0; j < 4; ++j) {
        int row = wc * 64 + j * 16 + (lane & 15);
        int byte = ((row << 7) + kb) ^ ((row & 7) << 4);
        bfr[j] = *reinterpret_cast<const short8*>((const char*)(&Bs[cur][0]) + byte);
      }
      __builtin_amdgcn_s_setprio(1);
      #pragma unroll
      for (int i = 0; i < 4; ++i)
        #pragma unroll
        for (int j = 0; j < 4; ++j)
          acc[i][j] = mfma16(af[i], bfr[j], acc[i][j]);
      __builtin_amdgcn_s_setprio(0);
    }
    __syncthreads();
    cur ^= 1;
  }

  #pragma unroll
  for (int j = 0; j < 4; ++j) {
    int col = bn + wc * 64 + j * 16 + (lane & 15);
    float bv = bias[col];
    #pragma unroll
    for (int i = 0; i < 4; ++i) {
      int row0 = bm + wr * 64 + i * 16 + ((lane >> 4) << 2);
      #pragma unroll
      for (int r = 0; r < 4; ++r) {
        float v = (acc[i][j][r] + bv) * alpha;
        if constexpr (OUT_F32)
          ((float*)Cp)[(size_t)(row0 + r) * N + col] = v;
        else
          ((short*)Cp)[(size_t)(row0 + r) * N + col] = bf16r(v);
      }
    }
  }
}

// ---------------- flash attention, 8-warp swapped-QK^T (R9 VERBATIM — green) ----------------
// Q: (B,T,H*64) bf16 pre-scaled by SCALE*log2e. K/V: (B,T,G*64) bf16. O: (B,T,H*64) bf16.
// Per block: 256 q-rows (8 warps x 32), KVBLK=64, 32x32x16 MFMA.
// S^T = mfma(K, Q): col=q=lane&31 -> lane-local softmax state (m,l).
// LEDGER — refuted changes to this kernel (do not re-try without new theory):
//  * fixed-m=0 softmax: FAILS here (R5-R7, absmax ~0.04; passes in 4-warp R4)
//  * S-ahead pipeline: VGPR spill, +11MB scratch traffic (R10, 112 µs)
//  * s_setprio around MFMA: barrier-lockstep -> occupancy loss (R11, ~+7 µs)
//  * tree max/sum reductions: +4 VGPR crosses the 64-VGPR cliff (m69),
//    waves/CU ceiling halves, occupancy 35->21% (R12, +18 µs).
//  This kernel sits EXACTLY at VGPR=64 — any change costing registers loses.
__global__ __launch_bounds__(512) void k_attn(
    const short* __restrict__ Q, const short* __restrict__ Kg,
    const short* __restrict__ Vg, short* __restrict__ Op)
{
  constexpr int T = 2048;
  constexpr int NT = T / 64;

  // bijective XCD-chunked swizzle: 512 blocks -> 64 contiguous per XCD
  const int orig = blockIdx.x;
  const int wgid = (orig & 7) * 64 + (orig >> 3);
  const int bh = wgid >> 3;            // 0..63 = b*32+h
  const int qb = wgid & 7;
  const int b = bh >> 5, h = bh & 31;
  const int g = h >> 2;
  const int q0 = qb * 256;

  const int t = threadIdx.x;
  const int lane = t & 63;
  const int wid = t >> 6;
  const int lo = lane & 31;
  const int hi = lane >> 5;

  __shared__ alignas(16) union {
    struct {
      short Kl[2][64 * 64];   // [key][d], XOR-swizzled bytes, gload_lds staged
      short Vt[2][64 * 72];   // [d][key], stride 72, reg-staged transpose
    } s;
    short Ol[8][32 * 72];     // epilogue O transpose, per-warp
  } sm;

  // Q fragments (B-operand): lane holds Q[q0w+lo][s*16 + hi*8 .. +8]
  const size_t qrow = (size_t)(b * T + q0 + wid * 32 + lo);
  short8 qf[4];
  #pragma unroll
  for (int s = 0; s < 4; ++s)
    qf[s] = *reinterpret_cast<const short8*>(Q + qrow * 2048 + h * 64 + s * 16 + hi * 8);

  f32x16 o0, o1;
  #pragma unroll
  for (int r = 0; r < 16; ++r) { o0[r] = 0.f; o1[r] = 0.f; }
  float m = -10000.f, l = 0.f;

  const short* Kbase = Kg + (size_t)(b * T) * 512 + g * 64;
  const short* Vbase = Vg + (size_t)(b * T) * 512 + g * 64;

  auto stageK = [&](int buf, int k0) {
    int lin = t * 16;                            // linear LDS byte dest
    int a = lin ^ (((lin >> 7) & 7) << 4);       // inverse-swizzled logical src
    int row = a >> 7;
    int col = (a & 127) >> 1;
    gload_lds16(Kbase + (size_t)(k0 + row) * 512 + col,
                (char*)(&sm.s.Kl[buf][0]) + (wid << 10));
  };
  short8 vreg;
  auto loadV = [&](int k0) {
    // thread t: key=lane, d-chunk=wid*8 (16B per lane)
    vreg = *reinterpret_cast<const short8*>(
        Vbase + (size_t)(k0 + lane) * 512 + wid * 8);
  };
  auto writeV = [&](int buf) {
    // V^T[d][key]: lanes write consecutive keys -> conflict-free
    #pragma unroll
    for (int e = 0; e < 8; ++e)
      sm.s.Vt[buf][(wid * 8 + e) * 72 + lane] = vreg[e];
  };

  stageK(0, 0);
  loadV(0);
  writeV(0);
  __syncthreads();

  int cur = 0;
  for (int kt = 0; kt < NT; ++kt) {
    const bool pf = (kt + 1 < NT);
    if (pf) { stageK(cur ^ 1, (kt + 1) * 64); loadV((kt + 1) * 64); }

    // ---- K frags (A-operand) + QK^T ----
    short8 kf[2][4];
    #pragma unroll
    for (int tt = 0; tt < 2; ++tt)
      #pragma unroll
      for (int s = 0; s < 4; ++s) {
        int row = tt * 32 + lo;
        int byte = ((row << 7) + (s << 5) + (hi << 4)) ^ ((row & 7) << 4);
        kf[tt][s] = *reinterpret_cast<const short8*>((const char*)(&sm.s.Kl[cur][0]) + byte);
      }
    f32x16 st0, st1;
    #pragma unroll
    for (int r = 0; r < 16; ++r) { st0[r] = 0.f; st1[r] = 0.f; }
    #pragma unroll
    for (int s = 0; s < 4; ++s) {
      st0 = mfma32(kf[0][s], qf[s], st0);
      st1 = mfma32(kf[1][s], qf[s], st1);
    }

    // ---- online softmax (log2 domain), lane-local q ----
    float mx = st0[0];
    #pragma unroll
    for (int r = 1; r < 16; ++r) mx = fmaxf(mx, st0[r]);
    #pragma unroll
    for (int r = 0; r < 16; ++r) mx = fmaxf(mx, st1[r]);
    mx = fmaxf(mx, __shfl_xor(mx, 32));
    if (!__all(mx - m <= 8.0f)) {      // T13 defer-max
      float mn = fmaxf(m, mx);
      float sc = fexp2(m - mn);
      m = mn; l *= sc;
      o0 = o0 * sc; o1 = o1 * sc;
    }
    float ssum = 0.f;
    #pragma unroll
    for (int r = 0; r < 16; ++r) { float e = fexp2(st0[r] - m); st0[r] = e; ssum += e; }
    #pragma unroll
    for (int r = 0; r < 16; ++r) { float e = fexp2(st1[r] - m); st1[r] = e; ssum += e; }
    ssum += __shfl_xor(ssum, 32);
    l += ssum;

    // ---- P -> bf16 B-frags: cvt_pk + cross-half shfl_xor redistribution ----
    short8 pb[4];
    #pragma unroll
    for (int tt = 0; tt < 2; ++tt) {
      const f32x16& sv = tt ? st1 : st0;
      #pragma unroll
      for (int half = 0; half < 2; ++half) {
        unsigned x1 = cvtpk(sv[half * 8 + 0], sv[half * 8 + 1]);
        unsigned x2 = cvtpk(sv[half * 8 + 2], sv[half * 8 + 3]);
        unsigned x3 = cvtpk(sv[half * 8 + 4], sv[half * 8 + 5]);
        unsigned x4 = cvtpk(sv[half * 8 + 6], sv[half * 8 + 7]);
        unsigned y1 = __shfl_xor(x1, 32);
        unsigned y2 = __shfl_xor(x2, 32);
        unsigned y3 = __shfl_xor(x3, 32);
        unsigned y4 = __shfl_xor(x4, 32);
        union { unsigned u[4]; short8 s8; } p;
        p.u[0] = hi ? y3 : x1;
        p.u[1] = hi ? y4 : x2;
        p.u[2] = hi ? x3 : y1;
        p.u[3] = hi ? x4 : y2;
        pb[tt * 2 + half] = p.s8;
      }
    }

    // ---- V^T frags (A-operand) + PV ----
    #pragma unroll
    for (int ks = 0; ks < 4; ++ks) {
      {
        int byte = (lo * 144) + (ks << 5) + (hi << 4);
        short8 va = *reinterpret_cast<const short8*>((const char*)(&sm.s.Vt[cur][0]) + byte);
        o0 = mfma32(va, pb[ks], o0);
      }
      {
        int byte = ((32 + lo) * 144) + (ks << 5) + (hi << 4);
        short8 va = *reinterpret_cast<const short8*>((const char*)(&sm.s.Vt[cur][0]) + byte);
        o1 = mfma32(va, pb[ks], o1);
      }
    }

    if (pf) writeV(cur ^ 1);
    __syncthreads();
    cur ^= 1;
  }

  // ---- epilogue: normalize, transpose via LDS, coalesced store ----
  float inv = 1.0f / l;
  #pragma unroll
  for (int dt = 0; dt < 2; ++dt) {
    const f32x16& ov = dt ? o1 : o0;
    #pragma unroll
    for (int r = 0; r < 16; r += 2) {
      unsigned d2 = cvtpk(ov[r] * inv, ov[r + 1] * inv);
      int dpos = dt * 32 + (r & 3) + 8 * (r >> 2) + 4 * hi;   // even
      *reinterpret_cast<unsigned*>((char*)(&sm.Ol[wid][0]) + (lo * 72 + dpos) * 2) = d2;
    }
  }
  __syncthreads();
  #pragma unroll
  for (int i = 0; i < 4; ++i) {
    int c = hi * 4 + i;
    short8 v = *reinterpret_cast<const short8*>((const char*)(&sm.Ol[wid][0]) + lo * 144 + c * 16);
    *reinterpret_cast<short8*>(Op + qrow * 2048 + h * 64 + c * 8) = v;
  }
}

// ---------------- launch (R12's validated dataflow) ----------------
// Workspace (62914560 B):
//   [0..8M) q_wb  [8M..10M) k_wb  [10M..12M) v_wb  [12M..20M) o_wb
//   R1 [20M..36M): kx -> Ap (attn out)
//   R2 [36M..52M): vx
//   [52M..56M) Kp   [56M..60M) Vp
// d_out (33.5 MB fp32 out) doubles as scratch BEFORE O-proj:
//   qx = d_out[0..16M) bf16, Qp = d_out[16M..32M) bf16 — O-proj fully overwrites.
extern "C" void kernel_launch(void* const* d_in, const int* in_sizes, int n_in,
                              void* d_out, int out_size, void* d_ws, size_t ws_size,
                              hipStream_t stream)
{
  const float* query = (const float*)d_in[0];
  const float* key   = (const float*)d_in[1];
  const float* value = (const float*)d_in[2];
  const float* q_w   = (const float*)d_in[3];
  const float* q_b   = (const float*)d_in[4];
  const float* k_w   = (const float*)d_in[5];
  const float* k_b   = (const float*)d_in[6];
  const float* v_w   = (const float*)d_in[7];
  const float* v_b   = (const float*)d_in[8];
  const float* o_w   = (const float*)d_in[9];
  const float* o_b   = (const float*)d_in[10];
  float* out = (float*)d_out;

  char* ws = (char*)d_ws;
  short* q_wb = (short*)(ws);
  short* k_wb = (short*)(ws + 8388608);
  short* v_wb = (short*)(ws + 10485760);
  short* o_wb = (short*)(ws + 12582912);
  short* R1   = (short*)(ws + 20971520);   // kx -> Ap
  short* R2   = (short*)(ws + 37748736);   // vx
  short* Kp   = (short*)(ws + 54525952);
  short* Vp   = (short*)(ws + 58720256);

  short* qx = (short*)d_out;                       // 16777216 B
  short* Qp = (short*)((char*)d_out + 16777216);   // 16777216 B

  const float ALPHA_Q = 0.125f * 1.4426950408889634f;  // SCALE * log2(e)

  // all 4 weight cvts in one dispatch; all 3 activation cvts in one dispatch
  k_cvtw<<<dim3(4096, 1, 4), 256, 0, stream>>>(
      q_w, q_wb, o_w, o_wb, k_w, k_wb, v_w, v_wb, 1048576, 262144);
  k_cvta<<<dim3(8192, 1, 3), 256, 0, stream>>>(
      query, qx, key, R1, value, R2, 2097152);

  // Q-proj (qx@d_out -> Qp@d_out)
  k_gemm<false, false><<<dim3(16, 32), 256, 0, stream>>>(
      qx, q_wb, q_b, Qp, nullptr, nullptr, nullptr, nullptr, 4096, 2048, 2048, ALPHA_Q);

  // fused K-proj / V-proj (R1,R2 -> Kp,Vp)
  k_gemm<false, true><<<dim3(4, 32, 2), 256, 0, stream>>>(
      R1, k_wb, k_b, Kp, R2, v_wb, v_b, Vp, 4096, 512, 2048, 1.0f);

  // attention (Qp@d_out, Kp, Vp -> Ap@R1; kx dead)
  k_attn<<<dim3(512), dim3(512), 0, stream>>>(Qp, Kp, Vp, R1);

  // O-proj (Ap@R1 -> out; overwrites ALL of d_out)
  k_gemm<true, false><<<dim3(16, 32), 256, 0, stream>>>(
      R1, o_wb, o_b, out, nullptr, nullptr, nullptr, nullptr, 4096, 2048, 2048, 1.0f);
}